// Round 8
// baseline (109.109 us; speedup 1.0000x reference)
//
#include <hip/hip_runtime.h>
#include <hip/hip_bf16.h>
#include <stdint.h>

typedef short s16x8 __attribute__((ext_vector_type(8)));
typedef float f32x4 __attribute__((ext_vector_type(4)));

static constexpr int DDIM = 256;
static constexpr float TEN_LOG2E = 14.4269504088896340736f; // 10 * log2(e)

// ---------------- Kernel 1: normalize + pack into MFMA-fragment order ----------------
// 512 blocks x 256 threads; block g handles rows [16g, 16g+16). Output layout:
// packed[((g*8 + kt)*64 + lane)*8 .. +8] = bf16 P[16g + (lane&15)][kt*32 + (lane>>4)*8 ..]
// Each (group, kt) fragment is one contiguous 1KB block in exact lane order -> a
// fragment load is one coalesced 16B/lane global_load_dwordx4.
// Also zero-inits row_s[8192] (blocks 0..7) and out[0] (block 0).
__global__ __launch_bounds__(256) void normalize_pack_kernel(
    const float* __restrict__ zi, const float* __restrict__ zj,
    ushort* __restrict__ packed, float* __restrict__ row_s, float* __restrict__ out)
{
    __shared__ ushort lds[16 * 256];

    if (blockIdx.x < 8) {
        ((float4*)row_s)[blockIdx.x * 256 + threadIdx.x] = (float4){0.f, 0.f, 0.f, 0.f};
        if (blockIdx.x == 0 && threadIdx.x == 0) out[0] = 0.0f;
    }

    const int t = threadIdx.x;
    const int r = t >> 4;            // 0..15: row within group
    const int c = t & 15;            // 16 threads per row
    const int row = blockIdx.x * 16 + r;
    const float* src = (row < 4096) ? (zi + (size_t)row * DDIM)
                                    : (zj + (size_t)(row - 4096) * DDIM);
    float4 v[4];
    #pragma unroll
    for (int j = 0; j < 4; ++j) v[j] = ((const float4*)src)[c + j * 16];

    float ss = 0.0f;
    #pragma unroll
    for (int j = 0; j < 4; ++j)
        ss += v[j].x * v[j].x + v[j].y * v[j].y + v[j].z * v[j].z + v[j].w * v[j].w;
    ss += __shfl_xor(ss, 1, 64);
    ss += __shfl_xor(ss, 2, 64);
    ss += __shfl_xor(ss, 4, 64);
    ss += __shfl_xor(ss, 8, 64);
    const float inv = 1.0f / fmaxf(sqrtf(ss), 1e-8f);

    #pragma unroll
    for (int j = 0; j < 4; ++j) {
        ushort4 o;
        o.x = __builtin_bit_cast(unsigned short, __float2bfloat16(v[j].x * inv));
        o.y = __builtin_bit_cast(unsigned short, __float2bfloat16(v[j].y * inv));
        o.z = __builtin_bit_cast(unsigned short, __float2bfloat16(v[j].z * inv));
        o.w = __builtin_bit_cast(unsigned short, __float2bfloat16(v[j].w * inv));
        *(ushort4*)(lds + r * 256 + (c + j * 16) * 4) = o;
    }
    __syncthreads();

    #pragma unroll
    for (int h = 0; h < 2; ++h) {
        const int idx  = h * 256 + t;
        const int kt   = idx >> 6;
        const int lane = idx & 63;
        const int q    = lane >> 4;
        const int l15  = lane & 15;
        s16x8 frag = *(const s16x8*)(lds + l15 * 256 + kt * 32 + q * 8);
        ((s16x8*)packed)[(size_t)(blockIdx.x * 8 + kt) * 64 + lane] = frag;
    }
}

// ---------------- Kernel 2: 256x256 Gram tiles, barrier-free direct-to-register ------
// 528 blocks = 32*33/2 upper-triangle 256x256 tiles, 8 waves (512 thr), wave grid 4x2,
// per-wave 64x128 output (acc[4][8]). NO LDS staging, NO k-loop barriers: the 4 MB
// packed array is L2-resident (4 MB/XCD), so per Common-mistake #7 staging it through
// LDS was pure overhead — worse, the per-kt __syncthreads drain exposed worst-case
// load latency to the whole (single-resident) block in lockstep. Here each wave loads
// its 12 fragments (4 A + 8 B, 16B/lane coalesced) straight into registers with a
// 1-step software pipeline: two statically-named register sets (kt fully unrolled ->
// all indices compile-time), loads for kt+1 issued before the 32 MFMAs of kt, so the
// compiler places s_waitcnt vmcnt(N) before first use one full kt (~300+ cy) after
// issue. Waves slip freely; the co-scheduled 2nd wave per SIMD covers residual stalls.
// Cost: per-wave A/B duplication -> ~405 MB L2 reads (~12 us chip floor) vs 8.5 us
// MFMA floor. Registers ~250 (128 acc + 96 operands + addr) -> launch_bounds(512,2)
// caps at 256/wave, 2 waves/SIMD. Epilogue unchanged from round 7 (verified).
__global__ __launch_bounds__(512, 2) void gram256_kernel(
    const ushort* __restrict__ packed,
    float* __restrict__ row_s,
    float* __restrict__ pos_out)
{
    __shared__ float rsum_lds[8][64];     // per-wave row partials (disjoint)
    __shared__ float csum_lds[8][128];    // per-wave col partials (disjoint)

    const int tid  = threadIdx.x;
    const int w    = tid >> 6;           // 0..7
    const int lane = tid & 63;
    const int q    = lane >> 4;
    const int l15  = lane & 15;
    const int wr   = w >> 1;             // 0..3: 64-row band
    const int wc   = w & 1;              // 0..1: 128-col band

    // ---- upper-triangle decode over 32x32 tile grid: block b -> (ti, tj), ti<=tj ----
    const int b = blockIdx.x;
    int ti = (int)(32.5f - sqrtf(32.5f * 32.5f - 2.0f * (float)b));
    while ((ti + 1) * 32 - ((ti + 1) * ti) / 2 <= b) ++ti;
    while (ti * 32 - (ti * (ti - 1)) / 2 > b) --ti;
    const int tj = ti + (b - (ti * 32 - (ti * (ti - 1)) / 2));
    const int r0 = ti * 256, c0 = tj * 256;
    const bool diag  = (ti == tj);
    const bool ptile = (tj == ti + 16);   // contains positive-pair diagonal (offset 4096)

    // per-wave fragment bases: A group (ti*16 + wr*4 + mi), B group (tj*16 + wc*8 + ni)
    // fragment (g, kt) lives at packed + g*4096 + kt*512 ushorts, + lane*8
    const ushort* paf = packed + (size_t)(ti * 16 + wr * 4) * 4096 + (size_t)lane * 8;
    const ushort* pbf = packed + (size_t)(tj * 16 + wc * 8) * 4096 + (size_t)lane * 8;

    f32x4 acc[4][8];
    #pragma unroll
    for (int mi = 0; mi < 4; ++mi)
        #pragma unroll
        for (int ni = 0; ni < 8; ++ni)
            acc[mi][ni] = (f32x4){0.f, 0.f, 0.f, 0.f};

    // two register sets for the 1-step pipeline (static names after full unroll)
    s16x8 afA[4], bfA[8], afB[4], bfB[8];

    // prologue: kt=0 fragments into set A
    #pragma unroll
    for (int mi = 0; mi < 4; ++mi)
        afA[mi] = *(const s16x8*)(paf + (size_t)mi * 4096);
    #pragma unroll
    for (int ni = 0; ni < 8; ++ni)
        bfA[ni] = *(const s16x8*)(pbf + (size_t)ni * 4096);

    #pragma unroll
    for (int kt = 0; kt < 8; ++kt) {
        s16x8* afc = (kt & 1) ? afB : afA;   // compile-time after unroll
        s16x8* bfc = (kt & 1) ? bfB : bfA;
        s16x8* afn = (kt & 1) ? afA : afB;
        s16x8* bfn = (kt & 1) ? bfA : bfB;

        if (kt < 7) {   // issue kt+1's 12 loads before kt's MFMAs
            #pragma unroll
            for (int mi = 0; mi < 4; ++mi)
                afn[mi] = *(const s16x8*)(paf + (size_t)mi * 4096 + (size_t)(kt + 1) * 512);
            #pragma unroll
            for (int ni = 0; ni < 8; ++ni)
                bfn[ni] = *(const s16x8*)(pbf + (size_t)ni * 4096 + (size_t)(kt + 1) * 512);
        }

        #pragma unroll
        for (int mi = 0; mi < 4; ++mi)
            #pragma unroll
            for (int ni = 0; ni < 8; ++ni)
                acc[mi][ni] = __builtin_amdgcn_mfma_f32_16x16x32_bf16(
                    afc[mi], bfc[ni], acc[mi][ni], 0, 0, 0);
    }

    // ---- epilogue: exp, diag mask, positive extraction, row+col partial sums ----
    // C/D layout (16x16): col = lane&15, row = q*4 + r
    float rsum[4][4];
    float csum[8] = {0.f, 0.f, 0.f, 0.f, 0.f, 0.f, 0.f, 0.f};
    #pragma unroll
    for (int mi = 0; mi < 4; ++mi)
        #pragma unroll
        for (int r = 0; r < 4; ++r) rsum[mi][r] = 0.0f;

    #pragma unroll
    for (int mi = 0; mi < 4; ++mi)
        #pragma unroll
        for (int ni = 0; ni < 8; ++ni)
            #pragma unroll
            for (int r = 0; r < 4; ++r) {
                const int lr = wr * 64 + mi * 16 + q * 4 + r;    // local row in 256
                const int lc = wc * 128 + ni * 16 + l15;         // local col in 256
                float e = exp2f(acc[mi][ni][r] * TEN_LOG2E);
                if (diag && lr == lc) e = 0.0f;                  // mask self-similarity
                rsum[mi][r] += e;
                csum[ni]    += e;
                if (ptile && lr == lc) {                         // positive: col=row+4096
                    const float v = acc[mi][ni][r] * 10.0f;
                    pos_out[r0 + lr] = v;
                    pos_out[c0 + lr] = v;
                }
            }

    // row partials: reduce across 16 lanes (cols) per quad; lanes l15==0 store 64 rows
    #pragma unroll
    for (int mi = 0; mi < 4; ++mi)
        #pragma unroll
        for (int r = 0; r < 4; ++r) {
            float v = rsum[mi][r];
            v += __shfl_xor(v, 1, 64);
            v += __shfl_xor(v, 2, 64);
            v += __shfl_xor(v, 4, 64);
            v += __shfl_xor(v, 8, 64);
            if (l15 == 0) rsum_lds[w][mi * 16 + q * 4 + r] = v;
        }
    // col partials: reduce across 4 row-quads; lanes 0..15 store 128 cols
    #pragma unroll
    for (int ni = 0; ni < 8; ++ni) {
        float v = csum[ni];
        v += __shfl_xor(v, 16, 64);
        v += __shfl_xor(v, 32, 64);
        if (lane < 16) csum_lds[w][ni * 16 + l15] = v;
    }

    __syncthreads();

    // combine wave partials; one global atomic per row (tid<256) / per col (tid>=256)
    if (tid < 256) {
        const int rr  = tid & 63;
        const int wr2 = tid >> 6;
        const float v = rsum_lds[wr2 * 2 + 0][rr] + rsum_lds[wr2 * 2 + 1][rr];
        atomicAdd(&row_s[r0 + tid], v);
    } else if (!diag) {
        const int c   = tid - 256;
        const int wcc = c >> 7;
        const int cc  = c & 127;
        const float v = csum_lds[0 * 2 + wcc][cc] + csum_lds[1 * 2 + wcc][cc]
                      + csum_lds[2 * 2 + wcc][cc] + csum_lds[3 * 2 + wcc][cc];
        atomicAdd(&row_s[c0 + c], v);
    }
}

// ---------------- Kernel 3: finalize loss ----------------
__global__ __launch_bounds__(256) void finalize_kernel(
    const float* __restrict__ row_s, const float* __restrict__ pos,
    float* __restrict__ out)
{
    const int i = blockIdx.x * 256 + threadIdx.x;   // float4 index, 2048 total
    float4 s = ((const float4*)row_s)[i];
    float4 p = ((const float4*)pos)[i];
    float local = (__logf(s.x) - p.x) + (__logf(s.y) - p.y)
                + (__logf(s.z) - p.z) + (__logf(s.w) - p.w);
    #pragma unroll
    for (int off = 32; off > 0; off >>= 1) local += __shfl_xor(local, off, 64);
    __shared__ float red[4];
    if ((threadIdx.x & 63) == 0) red[threadIdx.x >> 6] = local;
    __syncthreads();
    if (threadIdx.x == 0)
        atomicAdd(out, (red[0] + red[1] + red[2] + red[3]) * (1.0f / 8192.0f));
}

// ---------------- Launch ----------------
extern "C" void kernel_launch(void* const* d_in, const int* in_sizes, int n_in,
                              void* d_out, int out_size, void* d_ws, size_t ws_size,
                              hipStream_t stream)
{
    const float* zi = (const float*)d_in[0];
    const float* zj = (const float*)d_in[1];

    ushort* packed = (ushort*)d_ws;                                    // 4 MB fragment-order bf16
    float* row_s   = (float*)((char*)d_ws + (4u << 20));               // 8192 fp32
    float* pos     = (float*)((char*)d_ws + (4u << 20) + (32u << 10)); // 8192 fp32
    float* out     = (float*)d_out;

    hipLaunchKernelGGL(normalize_pack_kernel, dim3(512), dim3(256), 0, stream,
                       zi, zj, packed, row_s, out);
    hipLaunchKernelGGL(gram256_kernel, dim3(528), dim3(512), 0, stream,
                       packed, row_s, pos);
    hipLaunchKernelGGL(finalize_kernel, dim3(8), dim3(256), 0, stream, row_s, pos, out);
}

// Round 9
// 102.612 us; speedup vs baseline: 1.0633x; 1.0633x over previous
//
#include <hip/hip_runtime.h>
#include <hip/hip_bf16.h>
#include <stdint.h>

typedef short s16x8 __attribute__((ext_vector_type(8)));
typedef float f32x4 __attribute__((ext_vector_type(4)));

static constexpr int DDIM = 256;
static constexpr float TEN_LOG2E = 14.4269504088896340736f; // 10 * log2(e)

using u32_glb = __attribute__((address_space(1))) unsigned int;
using u32_lds = __attribute__((address_space(3))) unsigned int;

// ---------------- Kernel 1: normalize + pack into MFMA-fragment order ----------------
// 512 blocks x 256 threads; block g handles rows [16g, 16g+16). Output layout:
// packed[((g*8 + kt)*64 + lane)*8 .. +8] = bf16 P[16g + (lane&15)][kt*32 + (lane>>4)*8 ..]
// Each (group, kt) fragment is one contiguous 1KB block in exact lane order.
// Also zero-inits row_s[8192] (blocks 0..7) and out[0] (block 0).
__global__ __launch_bounds__(256) void normalize_pack_kernel(
    const float* __restrict__ zi, const float* __restrict__ zj,
    ushort* __restrict__ packed, float* __restrict__ row_s, float* __restrict__ out)
{
    __shared__ ushort lds[16 * 256];

    if (blockIdx.x < 8) {
        ((float4*)row_s)[blockIdx.x * 256 + threadIdx.x] = (float4){0.f, 0.f, 0.f, 0.f};
        if (blockIdx.x == 0 && threadIdx.x == 0) out[0] = 0.0f;
    }

    const int t = threadIdx.x;
    const int r = t >> 4;            // 0..15: row within group
    const int c = t & 15;            // 16 threads per row
    const int row = blockIdx.x * 16 + r;
    const float* src = (row < 4096) ? (zi + (size_t)row * DDIM)
                                    : (zj + (size_t)(row - 4096) * DDIM);
    float4 v[4];
    #pragma unroll
    for (int j = 0; j < 4; ++j) v[j] = ((const float4*)src)[c + j * 16];

    float ss = 0.0f;
    #pragma unroll
    for (int j = 0; j < 4; ++j)
        ss += v[j].x * v[j].x + v[j].y * v[j].y + v[j].z * v[j].z + v[j].w * v[j].w;
    ss += __shfl_xor(ss, 1, 64);
    ss += __shfl_xor(ss, 2, 64);
    ss += __shfl_xor(ss, 4, 64);
    ss += __shfl_xor(ss, 8, 64);
    const float inv = 1.0f / fmaxf(sqrtf(ss), 1e-8f);

    #pragma unroll
    for (int j = 0; j < 4; ++j) {
        ushort4 o;
        o.x = __builtin_bit_cast(unsigned short, __float2bfloat16(v[j].x * inv));
        o.y = __builtin_bit_cast(unsigned short, __float2bfloat16(v[j].y * inv));
        o.z = __builtin_bit_cast(unsigned short, __float2bfloat16(v[j].z * inv));
        o.w = __builtin_bit_cast(unsigned short, __float2bfloat16(v[j].w * inv));
        *(ushort4*)(lds + r * 256 + (c + j * 16) * 4) = o;
    }
    __syncthreads();

    #pragma unroll
    for (int h = 0; h < 2; ++h) {
        const int idx  = h * 256 + t;
        const int kt   = idx >> 6;
        const int lane = idx & 63;
        const int q    = lane >> 4;
        const int l15  = lane & 15;
        s16x8 frag = *(const s16x8*)(lds + l15 * 256 + kt * 32 + q * 8);
        ((s16x8*)packed)[(size_t)(blockIdx.x * 8 + kt) * 64 + lane] = frag;
    }
}

// ---------------- Kernel 2: 256x256 Gram tiles + XCD-bijective tile swizzle ----------
// Base = round-7 structure (best measured: LDS double-buffer, drain sync). One new
// mechanism under test: T1 XCD swizzle. Diagnosis: three maximally-different k-loop
// schedules all land at 47-53us with block lifetime ~20us vs ~3us of work ->
// latency-inflated L2/L3 service on the shared 4MB packed array is the bottleneck,
// not the schedule. Default dispatch scatters consecutive blocks across XCDs, so each
// XCD's L2 sees a near-random subset of the whole triangle -> panel working set = all
// 4MB -> L3-latency misses. 528 tiles = 8*66 exactly: tile = (b&7)*66 + (b>>3) gives
// each XCD a contiguous run of upper-triangle tiles sharing A-row panels -> per-XCD
// hot set shrinks to a few panels -> L2-hit latency. Also: exp2f -> raw v_exp_f32
// builtin (drops libm wrapper VALU in the 128-value epilogue).
__global__ __launch_bounds__(512, 1) void gram256_kernel(
    const ushort* __restrict__ packed,
    float* __restrict__ row_s,
    float* __restrict__ pos_out)
{
    __shared__ ushort sbuf[2][32][512];   // 64 KB: frags 0..15 = A groups, 16..31 = B
    __shared__ float rsum_lds[8][64];     // per-wave row partials (wave rows)
    __shared__ float csum_lds[8][128];    // per-wave col partials (wave cols)

    const int tid  = threadIdx.x;
    const int w    = tid >> 6;           // 0..7
    const int lane = tid & 63;
    const int q    = lane >> 4;
    const int l15  = lane & 15;
    const int wr   = w >> 1;             // 0..3: 64-row band
    const int wc   = w & 1;              // 0..1: 128-col band

    // ---- XCD-bijective swizzle: 528 = 8 XCDs x 66 tiles, contiguous run per XCD ----
    const int b = ((int)blockIdx.x & 7) * 66 + ((int)blockIdx.x >> 3);

    // ---- upper-triangle decode over 32x32 tile grid: b -> (ti, tj), ti<=tj ----
    int ti = (int)(32.5f - sqrtf(32.5f * 32.5f - 2.0f * (float)b));
    while ((ti + 1) * 32 - ((ti + 1) * ti) / 2 <= b) ++ti;
    while (ti * 32 - (ti * (ti - 1)) / 2 > b) --ti;
    const int tj = ti + (b - (ti * 32 - (ti * (ti - 1)) / 2));
    const int r0 = ti * 256, c0 = tj * 256;
    const bool diag  = (ti == tj);
    const bool ptile = (tj == ti + 16);   // contains positive-pair diagonal (offset 4096)

    // staging sources: wave w stages fragments f = 4w..4w+3 (32 total)
    // f<16 -> A group ti*16+f ; f>=16 -> B group tj*16+(f-16)
    const ushort* sbase[4];
    #pragma unroll
    for (int si = 0; si < 4; ++si) {
        const int f = w * 4 + si;
        const int g = (f < 16) ? (ti * 16 + f) : (tj * 16 + (f - 16));
        sbase[si] = packed + (size_t)g * 4096 + (size_t)lane * 8;   // kt=0 fragment
    }
    auto stagek = [&](int buf, int kt) {
        #pragma unroll
        for (int si = 0; si < 4; ++si) {
            const int f = w * 4 + si;
            __builtin_amdgcn_global_load_lds(
                (const u32_glb*)(sbase[si] + kt * 512),
                (u32_lds*)&sbuf[buf][f][0], 16, 0, 0);
        }
    };

    f32x4 acc[4][8];
    #pragma unroll
    for (int mi = 0; mi < 4; ++mi)
        #pragma unroll
        for (int ni = 0; ni < 8; ++ni)
            acc[mi][ni] = (f32x4){0.f, 0.f, 0.f, 0.f};

    stagek(0, 0);
    __syncthreads();   // buffer 0 ready (vmcnt drained by syncthreads semantics)

    for (int kt = 0; kt < 8; ++kt) {
        const int cur = kt & 1;
        if (kt < 7) stagek(cur ^ 1, kt + 1);   // next slice's loads fly under compute

        s16x8 af[4], bfr[8];
        #pragma unroll
        for (int mi = 0; mi < 4; ++mi)
            af[mi] = *(const s16x8*)&sbuf[cur][wr * 4 + mi][lane * 8];
        #pragma unroll
        for (int ni = 0; ni < 8; ++ni)
            bfr[ni] = *(const s16x8*)&sbuf[cur][16 + wc * 8 + ni][lane * 8];

        #pragma unroll
        for (int mi = 0; mi < 4; ++mi)
            #pragma unroll
            for (int ni = 0; ni < 8; ++ni)
                acc[mi][ni] = __builtin_amdgcn_mfma_f32_16x16x32_bf16(
                    af[mi], bfr[ni], acc[mi][ni], 0, 0, 0);

        __syncthreads();   // all reads of cur done + staged cur^1 landed
    }

    // ---- epilogue: exp, diag mask, positive extraction, row+col partial sums ----
    // C/D layout (16x16): col = lane&15, row = q*4 + r
    float rsum[4][4];
    float csum[8] = {0.f, 0.f, 0.f, 0.f, 0.f, 0.f, 0.f, 0.f};
    #pragma unroll
    for (int mi = 0; mi < 4; ++mi)
        #pragma unroll
        for (int r = 0; r < 4; ++r) rsum[mi][r] = 0.0f;

    #pragma unroll
    for (int mi = 0; mi < 4; ++mi)
        #pragma unroll
        for (int ni = 0; ni < 8; ++ni)
            #pragma unroll
            for (int r = 0; r < 4; ++r) {
                const int lr = wr * 64 + mi * 16 + q * 4 + r;    // local row in 256
                const int lc = wc * 128 + ni * 16 + l15;         // local col in 256
                // raw v_exp_f32 (arg in [-14.5,14.5]: no denorm/range issues)
                float e = __builtin_amdgcn_exp2f(acc[mi][ni][r] * TEN_LOG2E);
                if (diag && lr == lc) e = 0.0f;                  // mask self-similarity
                rsum[mi][r] += e;
                csum[ni]    += e;
                if (ptile && lr == lc) {                         // positive: col=row+4096
                    const float v = acc[mi][ni][r] * 10.0f;
                    pos_out[r0 + lr] = v;
                    pos_out[c0 + lr] = v;
                }
            }

    // row partials: reduce across 16 lanes (cols) per quad; lanes l15==0 store 64 rows
    #pragma unroll
    for (int mi = 0; mi < 4; ++mi)
        #pragma unroll
        for (int r = 0; r < 4; ++r) {
            float v = rsum[mi][r];
            v += __shfl_xor(v, 1, 64);
            v += __shfl_xor(v, 2, 64);
            v += __shfl_xor(v, 4, 64);
            v += __shfl_xor(v, 8, 64);
            if (l15 == 0) rsum_lds[w][mi * 16 + q * 4 + r] = v;
        }
    // col partials: reduce across 4 row-quads; lanes 0..15 store 128 cols
    #pragma unroll
    for (int ni = 0; ni < 8; ++ni) {
        float v = csum[ni];
        v += __shfl_xor(v, 16, 64);
        v += __shfl_xor(v, 32, 64);
        if (lane < 16) csum_lds[w][ni * 16 + l15] = v;
    }

    __syncthreads();

    // combine wave partials; one global atomic per row (tid<256) / per col (tid>=256)
    if (tid < 256) {
        const int rr  = tid & 63;
        const int wr2 = tid >> 6;
        const float v = rsum_lds[wr2 * 2 + 0][rr] + rsum_lds[wr2 * 2 + 1][rr];
        atomicAdd(&row_s[r0 + tid], v);
    } else if (!diag) {
        const int c   = tid - 256;
        const int wcc = c >> 7;
        const int cc  = c & 127;
        const float v = csum_lds[0 * 2 + wcc][cc] + csum_lds[1 * 2 + wcc][cc]
                      + csum_lds[2 * 2 + wcc][cc] + csum_lds[3 * 2 + wcc][cc];
        atomicAdd(&row_s[c0 + c], v);
    }
}

// ---------------- Kernel 3: finalize loss ----------------
__global__ __launch_bounds__(256) void finalize_kernel(
    const float* __restrict__ row_s, const float* __restrict__ pos,
    float* __restrict__ out)
{
    const int i = blockIdx.x * 256 + threadIdx.x;   // float4 index, 2048 total
    float4 s = ((const float4*)row_s)[i];
    float4 p = ((const float4*)pos)[i];
    float local = (__logf(s.x) - p.x) + (__logf(s.y) - p.y)
                + (__logf(s.z) - p.z) + (__logf(s.w) - p.w);
    #pragma unroll
    for (int off = 32; off > 0; off >>= 1) local += __shfl_xor(local, off, 64);
    __shared__ float red[4];
    if ((threadIdx.x & 63) == 0) red[threadIdx.x >> 6] = local;
    __syncthreads();
    if (threadIdx.x == 0)
        atomicAdd(out, (red[0] + red[1] + red[2] + red[3]) * (1.0f / 8192.0f));
}

// ---------------- Launch ----------------
extern "C" void kernel_launch(void* const* d_in, const int* in_sizes, int n_in,
                              void* d_out, int out_size, void* d_ws, size_t ws_size,
                              hipStream_t stream)
{
    const float* zi = (const float*)d_in[0];
    const float* zj = (const float*)d_in[1];

    ushort* packed = (ushort*)d_ws;                                    // 4 MB fragment-order bf16
    float* row_s   = (float*)((char*)d_ws + (4u << 20));               // 8192 fp32
    float* pos     = (float*)((char*)d_ws + (4u << 20) + (32u << 10)); // 8192 fp32
    float* out     = (float*)d_out;

    hipLaunchKernelGGL(normalize_pack_kernel, dim3(512), dim3(256), 0, stream,
                       zi, zj, packed, row_s, out);
    hipLaunchKernelGGL(gram256_kernel, dim3(528), dim3(512), 0, stream,
                       packed, row_s, pos);
    hipLaunchKernelGGL(finalize_kernel, dim3(8), dim3(256), 0, stream, row_s, pos, out);
}

// Round 13
// 100.701 us; speedup vs baseline: 1.0835x; 1.0190x over previous
//
#include <hip/hip_runtime.h>
#include <hip/hip_bf16.h>
#include <stdint.h>

typedef short s16x8 __attribute__((ext_vector_type(8)));
typedef float f32x4 __attribute__((ext_vector_type(4)));

static constexpr int DDIM = 256;
static constexpr float TEN_LOG2E = 14.4269504088896340736f; // 10 * log2(e)

using u32_glb = __attribute__((address_space(1))) unsigned int;
using u32_lds = __attribute__((address_space(3))) unsigned int;

// ---------------- Kernel 1: normalize + pack into MFMA-fragment order ----------------
// 512 blocks x 256 threads; block g handles rows [16g, 16g+16). Output layout:
// packed[((g*8 + kt)*64 + lane)*8 .. +8] = bf16 P[16g + (lane&15)][kt*32 + (lane>>4)*8 ..]
// Each (group, kt) fragment is one contiguous 1KB block in exact lane order.
// Also zero-inits row_s[8192] (blocks 0..7) and out[0] (block 0).
__global__ __launch_bounds__(256) void normalize_pack_kernel(
    const float* __restrict__ zi, const float* __restrict__ zj,
    ushort* __restrict__ packed, float* __restrict__ row_s, float* __restrict__ out)
{
    __shared__ ushort lds[16 * 256];

    if (blockIdx.x < 8) {
        ((float4*)row_s)[blockIdx.x * 256 + threadIdx.x] = (float4){0.f, 0.f, 0.f, 0.f};
        if (blockIdx.x == 0 && threadIdx.x == 0) out[0] = 0.0f;
    }

    const int t = threadIdx.x;
    const int r = t >> 4;            // 0..15: row within group
    const int c = t & 15;            // 16 threads per row
    const int row = blockIdx.x * 16 + r;
    const float* src = (row < 4096) ? (zi + (size_t)row * DDIM)
                                    : (zj + (size_t)(row - 4096) * DDIM);
    float4 v[4];
    #pragma unroll
    for (int j = 0; j < 4; ++j) v[j] = ((const float4*)src)[c + j * 16];

    float ss = 0.0f;
    #pragma unroll
    for (int j = 0; j < 4; ++j)
        ss += v[j].x * v[j].x + v[j].y * v[j].y + v[j].z * v[j].z + v[j].w * v[j].w;
    ss += __shfl_xor(ss, 1, 64);
    ss += __shfl_xor(ss, 2, 64);
    ss += __shfl_xor(ss, 4, 64);
    ss += __shfl_xor(ss, 8, 64);
    const float inv = 1.0f / fmaxf(sqrtf(ss), 1e-8f);

    #pragma unroll
    for (int j = 0; j < 4; ++j) {
        ushort4 o;
        o.x = __builtin_bit_cast(unsigned short, __float2bfloat16(v[j].x * inv));
        o.y = __builtin_bit_cast(unsigned short, __float2bfloat16(v[j].y * inv));
        o.z = __builtin_bit_cast(unsigned short, __float2bfloat16(v[j].z * inv));
        o.w = __builtin_bit_cast(unsigned short, __float2bfloat16(v[j].w * inv));
        *(ushort4*)(lds + r * 256 + (c + j * 16) * 4) = o;
    }
    __syncthreads();

    #pragma unroll
    for (int h = 0; h < 2; ++h) {
        const int idx  = h * 256 + t;
        const int kt   = idx >> 6;
        const int lane = idx & 63;
        const int q    = lane >> 4;
        const int l15  = lane & 15;
        s16x8 frag = *(const s16x8*)(lds + l15 * 256 + kt * 32 + q * 8);
        ((s16x8*)packed)[(size_t)(blockIdx.x * 8 + kt) * 64 + lane] = frag;
    }
}

// ---------------- Kernel 2: 256x256 tiles, ring-3 all-LDS, counted vmcnt -------------
// = R10's design (never actually run; R10 was an infra failure, and R11/R12's hybrid
// replacement had a real WAR race) resubmitted with the race mechanism closed.
// All-LDS staging, the sync pattern verified at 128^2 (R2: passed, absmax 0) on the
// tile structure verified at 256^2 (R7/R9: passed, absmax 0):
//   stagek = 4 global_load_lds per wave (32 frags/slot: 0..15 A, 16..31 B).
//   Prologue: S0, S1 -> vmcnt(4) retires S0 (S1's 4 in flight) -> barrier.
//   Iter kt<6: stage S(kt+2); end: vmcnt(4) retires S(kt+1), keeps S(kt+2) in flight.
//   kt==6: vmcnt(0) retires S7.  Barrier after each kt<7.
// RACE FIX (the R11/R12 lesson): __builtin_amdgcn_s_barrier is NOT an IR memory
// fence — the compiler could hoist the next iteration's stage between the waitcnt
// and the barrier, overwriting a slot other waves are still reading. An empty
// `asm volatile("" ::: "memory")` AFTER each barrier pins all memory ops below it
// (zero instructions emitted; unlike sched_barrier(0) it constrains only memory
// motion — m141's regression does not apply).
// Why depth-2 should finally pay at 256^2: per-kt compute ~320cy (vs 160cy at 128^2),
// so two iterations ~640cy >= the cold L2/L3 latency the drain-per-kt versions
// (R7/R9, 43us) expose serially. LDS 104KB static (legal: m201 example uses 128KB).
__global__ __launch_bounds__(512, 1) void gram256_kernel(
    const ushort* __restrict__ packed,
    float* __restrict__ row_s,
    float* __restrict__ pos_out)
{
    __shared__ ushort sbuf[3][32][512];   // 96 KB ring: frags 0..15 = A, 16..31 = B
    __shared__ float rsum_lds[8][64];     // per-wave row partials
    __shared__ float csum_lds[8][128];    // per-wave col partials

    const int tid  = threadIdx.x;
    const int w    = tid >> 6;           // 0..7
    const int lane = tid & 63;
    const int q    = lane >> 4;
    const int l15  = lane & 15;
    const int wr   = w >> 1;             // 0..3: 64-row band
    const int wc   = w & 1;              // 0..1: 128-col band

    // ---- XCD-bijective swizzle: 528 = 8 XCDs x 66 tiles, contiguous run per XCD ----
    const int b = ((int)blockIdx.x & 7) * 66 + ((int)blockIdx.x >> 3);

    // ---- upper-triangle decode over 32x32 tile grid: b -> (ti, tj), ti<=tj ----
    int ti = (int)(32.5f - sqrtf(32.5f * 32.5f - 2.0f * (float)b));
    while ((ti + 1) * 32 - ((ti + 1) * ti) / 2 <= b) ++ti;
    while (ti * 32 - (ti * (ti - 1)) / 2 > b) --ti;
    const int tj = ti + (b - (ti * 32 - (ti * (ti - 1)) / 2));
    const int r0 = ti * 256, c0 = tj * 256;
    const bool diag  = (ti == tj);
    const bool ptile = (tj == ti + 16);   // contains positive-pair diagonal (offset 4096)

    // staging sources: wave w stages fragments f = 4w..4w+3 (32 total)
    const ushort* sbase[4];
    #pragma unroll
    for (int si = 0; si < 4; ++si) {
        const int f = w * 4 + si;
        const int g = (f < 16) ? (ti * 16 + f) : (tj * 16 + (f - 16));
        sbase[si] = packed + (size_t)g * 4096 + (size_t)lane * 8;   // kt=0 fragment
    }
    auto stagek = [&](int slot, int kt) {
        #pragma unroll
        for (int si = 0; si < 4; ++si) {
            const int f = w * 4 + si;
            __builtin_amdgcn_global_load_lds(
                (const u32_glb*)(sbase[si] + kt * 512),
                (u32_lds*)&sbuf[slot][f][0], 16, 0, 0);
        }
    };

    f32x4 acc[4][8];
    #pragma unroll
    for (int mi = 0; mi < 4; ++mi)
        #pragma unroll
        for (int ni = 0; ni < 8; ++ni)
            acc[mi][ni] = (f32x4){0.f, 0.f, 0.f, 0.f};

    // prologue: fill ring slots 0,1 (kt=0,1); wait for kt=0's group only
    stagek(0, 0);
    stagek(1, 1);
    asm volatile("s_waitcnt vmcnt(4)" ::: "memory");
    __builtin_amdgcn_s_barrier();
    asm volatile("" ::: "memory");   // fence: no memory op hoists above the barrier

    for (int kt = 0; kt < 8; ++kt) {
        if (kt < 6) stagek((kt + 2) % 3, kt + 2);   // 2-ahead prefetch

        s16x8 af[4], bfr[8];
        #pragma unroll
        for (int mi = 0; mi < 4; ++mi)
            af[mi] = *(const s16x8*)&sbuf[kt % 3][wr * 4 + mi][lane * 8];
        #pragma unroll
        for (int ni = 0; ni < 8; ++ni)
            bfr[ni] = *(const s16x8*)&sbuf[kt % 3][16 + wc * 8 + ni][lane * 8];

        #pragma unroll
        for (int mi = 0; mi < 4; ++mi)
            #pragma unroll
            for (int ni = 0; ni < 8; ++ni)
                acc[mi][ni] = __builtin_amdgcn_mfma_f32_16x16x32_bf16(
                    af[mi], bfr[ni], acc[mi][ni], 0, 0, 0);

        // counted wait: S(kt+1) (oldest outstanding) retired; S(kt+2) stays in flight
        if (kt < 6)       asm volatile("s_waitcnt vmcnt(4)" ::: "memory");
        else if (kt == 6) asm volatile("s_waitcnt vmcnt(0)" ::: "memory");
        if (kt < 7) {
            __builtin_amdgcn_s_barrier();
            asm volatile("" ::: "memory");   // fence: next stage stays below barrier
        }
    }

    // ---- epilogue: exp, diag mask, positive extraction, row+col partial sums ----
    // C/D layout (16x16): col = lane&15, row = q*4 + r
    float rsum[4][4];
    float csum[8] = {0.f, 0.f, 0.f, 0.f, 0.f, 0.f, 0.f, 0.f};
    #pragma unroll
    for (int mi = 0; mi < 4; ++mi)
        #pragma unroll
        for (int r = 0; r < 4; ++r) rsum[mi][r] = 0.0f;

    #pragma unroll
    for (int mi = 0; mi < 4; ++mi)
        #pragma unroll
        for (int ni = 0; ni < 8; ++ni)
            #pragma unroll
            for (int r = 0; r < 4; ++r) {
                const int lr = wr * 64 + mi * 16 + q * 4 + r;    // local row in 256
                const int lc = wc * 128 + ni * 16 + l15;         // local col in 256
                float e = __builtin_amdgcn_exp2f(acc[mi][ni][r] * TEN_LOG2E);
                if (diag && lr == lc) e = 0.0f;                  // mask self-similarity
                rsum[mi][r] += e;
                csum[ni]    += e;
                if (ptile && lr == lc) {                         // positive: col=row+4096
                    const float v = acc[mi][ni][r] * 10.0f;
                    pos_out[r0 + lr] = v;
                    pos_out[c0 + lr] = v;
                }
            }

    // row partials: reduce across 16 lanes (cols) per quad; lanes l15==0 store 64 rows
    #pragma unroll
    for (int mi = 0; mi < 4; ++mi)
        #pragma unroll
        for (int r = 0; r < 4; ++r) {
            float v = rsum[mi][r];
            v += __shfl_xor(v, 1, 64);
            v += __shfl_xor(v, 2, 64);
            v += __shfl_xor(v, 4, 64);
            v += __shfl_xor(v, 8, 64);
            if (l15 == 0) rsum_lds[w][mi * 16 + q * 4 + r] = v;
        }
    // col partials: reduce across 4 row-quads; lanes 0..15 store 128 cols
    #pragma unroll
    for (int ni = 0; ni < 8; ++ni) {
        float v = csum[ni];
        v += __shfl_xor(v, 16, 64);
        v += __shfl_xor(v, 32, 64);
        if (lane < 16) csum_lds[w][ni * 16 + l15] = v;
    }

    __syncthreads();

    // combine wave partials; one global atomic per row (tid<256) / per col (tid>=256)
    if (tid < 256) {
        const int rr  = tid & 63;
        const int wr2 = tid >> 6;
        const float v = rsum_lds[wr2 * 2 + 0][rr] + rsum_lds[wr2 * 2 + 1][rr];
        atomicAdd(&row_s[r0 + tid], v);
    } else if (!diag) {
        const int c   = tid - 256;
        const int wcc = c >> 7;
        const int cc  = c & 127;
        const float v = csum_lds[0 * 2 + wcc][cc] + csum_lds[1 * 2 + wcc][cc]
                      + csum_lds[2 * 2 + wcc][cc] + csum_lds[3 * 2 + wcc][cc];
        atomicAdd(&row_s[c0 + c], v);
    }
}

// ---------------- Kernel 3: finalize loss ----------------
__global__ __launch_bounds__(256) void finalize_kernel(
    const float* __restrict__ row_s, const float* __restrict__ pos,
    float* __restrict__ out)
{
    const int i = blockIdx.x * 256 + threadIdx.x;   // float4 index, 2048 total
    float4 s = ((const float4*)row_s)[i];
    float4 p = ((const float4*)pos)[i];
    float local = (__logf(s.x) - p.x) + (__logf(s.y) - p.y)
                + (__logf(s.z) - p.z) + (__logf(s.w) - p.w);
    #pragma unroll
    for (int off = 32; off > 0; off >>= 1) local += __shfl_xor(local, off, 64);
    __shared__ float red[4];
    if ((threadIdx.x & 63) == 0) red[threadIdx.x >> 6] = local;
    __syncthreads();
    if (threadIdx.x == 0)
        atomicAdd(out, (red[0] + red[1] + red[2] + red[3]) * (1.0f / 8192.0f));
}

// ---------------- Launch ----------------
extern "C" void kernel_launch(void* const* d_in, const int* in_sizes, int n_in,
                              void* d_out, int out_size, void* d_ws, size_t ws_size,
                              hipStream_t stream)
{
    const float* zi = (const float*)d_in[0];
    const float* zj = (const float*)d_in[1];

    ushort* packed = (ushort*)d_ws;                                    // 4 MB fragment-order bf16
    float* row_s   = (float*)((char*)d_ws + (4u << 20));               // 8192 fp32
    float* pos     = (float*)((char*)d_ws + (4u << 20) + (32u << 10)); // 8192 fp32
    float* out     = (float*)d_out;

    hipLaunchKernelGGL(normalize_pack_kernel, dim3(512), dim3(256), 0, stream,
                       zi, zj, packed, row_s, out);
    hipLaunchKernelGGL(gram256_kernel, dim3(528), dim3(512), 0, stream,
                       packed, row_s, pos);
    hipLaunchKernelGGL(finalize_kernel, dim3(8), dim3(256), 0, stream, row_s, pos, out);
}

// Round 14
// 95.532 us; speedup vs baseline: 1.1421x; 1.0541x over previous
//
#include <hip/hip_runtime.h>
#include <hip/hip_bf16.h>
#include <stdint.h>

typedef float f32x4 __attribute__((ext_vector_type(4)));
typedef unsigned long u64x2 __attribute__((ext_vector_type(2)));

static constexpr int DDIM = 256;
static constexpr float TEN_LOG2E = 14.4269504088896340736f; // 10 * log2(e)

using u32_glb = __attribute__((address_space(1))) unsigned int;
using u32_lds = __attribute__((address_space(3))) unsigned int;

// ---------------- Kernel 1: normalize + pack fp8 into MFMA-fragment order -----------
// 512 blocks x 256 threads; block g handles rows [16g, 16g+16). fp8 e4m3 packing:
// half the panel bytes of bf16 at identical MFMA rate (16x16x32_fp8_fp8 = bf16 rate,
// same lane->(row, k=(lane>>4)*8+j) fragment map, 8 bytes/lane).
// Super-fragment layout (K=64 per stage step so global_load_lds keeps its 16B/lane
// width): group g, kt2 in 0..3 -> 1KB block at packed + g*4096 + kt2*1024:
//   bytes [0,512)   = frag kt=2*kt2   (fragment-lane f at f*8: P8[16g+(f&15)][kt*32+(f>>4)*8+j])
//   bytes [512,1024)= frag kt=2*kt2+1 (same layout)
// A lane's 16B stage slice = two consecutive fragment-lanes -> LDS lands linearly and
// ds_read_b64 at s*512 + lane*8 yields the sub-K fragment. Also zero-inits row_s/out.
__global__ __launch_bounds__(256) void normalize_pack_kernel(
    const float* __restrict__ zi, const float* __restrict__ zj,
    unsigned char* __restrict__ packed, float* __restrict__ row_s, float* __restrict__ out)
{
    __shared__ unsigned char lds8[16 * 256];   // fp8 row-major for this group

    if (blockIdx.x < 8) {
        ((float4*)row_s)[blockIdx.x * 256 + threadIdx.x] = (float4){0.f, 0.f, 0.f, 0.f};
        if (blockIdx.x == 0 && threadIdx.x == 0) out[0] = 0.0f;
    }

    const int t = threadIdx.x;
    const int r = t >> 4;            // 0..15: row within group
    const int c = t & 15;            // 16 threads per row
    const int row = blockIdx.x * 16 + r;
    const float* src = (row < 4096) ? (zi + (size_t)row * DDIM)
                                    : (zj + (size_t)(row - 4096) * DDIM);
    float4 v[4];
    #pragma unroll
    for (int j = 0; j < 4; ++j) v[j] = ((const float4*)src)[c + j * 16];

    float ss = 0.0f;
    #pragma unroll
    for (int j = 0; j < 4; ++j)
        ss += v[j].x * v[j].x + v[j].y * v[j].y + v[j].z * v[j].z + v[j].w * v[j].w;
    ss += __shfl_xor(ss, 1, 64);
    ss += __shfl_xor(ss, 2, 64);
    ss += __shfl_xor(ss, 4, 64);
    ss += __shfl_xor(ss, 8, 64);
    const float inv = 1.0f / fmaxf(sqrtf(ss), 1e-8f);

    // convert 4 floats -> 4 fp8 bytes (v_cvt_pk_fp8_f32: word0 = {x,y}, word1 = {z,w})
    #pragma unroll
    for (int j = 0; j < 4; ++j) {
        int pk = __builtin_amdgcn_cvt_pk_fp8_f32(v[j].x * inv, v[j].y * inv, 0, 0);
        pk     = __builtin_amdgcn_cvt_pk_fp8_f32(v[j].z * inv, v[j].w * inv, pk, 1);
        *(unsigned int*)(lds8 + r * 256 + c * 4 + j * 64) = (unsigned int)pk;
    }
    __syncthreads();

    // repack: 4 super-frags x 64 slots of 16B = 256 writes; thread t -> (kt2 = t>>6,
    // slot p = t&63). Slot p covers fragment-lanes 2p',2p'+1 of frag kt = 2*kt2+(p>>5).
    {
        const int kt2 = t >> 6;
        const int p   = t & 63;
        const int kt  = kt2 * 2 + (p >> 5);
        const int pp  = p & 31;
        const int fl0 = pp * 2, fl1 = pp * 2 + 1;
        u64x2 o;
        o.x = *(const unsigned long*)(lds8 + (fl0 & 15) * 256 + kt * 32 + (fl0 >> 4) * 8);
        o.y = *(const unsigned long*)(lds8 + (fl1 & 15) * 256 + kt * 32 + (fl1 >> 4) * 8);
        *(u64x2*)(packed + (size_t)(blockIdx.x * 4 + kt2) * 1024 + (size_t)p * 16) = o;
    }
}

// ---------------- Kernel 2: 256x256 tiles fp8, ring-3 all-LDS, counted vmcnt ---------
// = R13's verified structure (passed, absmax 0) with fp8 panels: 4 K-steps of K=64
// (each = 2 sub-MFMAs of 16x16x32_fp8_fp8), staged bytes per step unchanged (32KB:
// 32 frags x 1KB super-frag) but TOTAL staged bytes halved (128KB vs 256KB) and the
// packed array is 2MB (vs 4MB) -> per-XCD compulsory fetch ~halves. Prefetch depth 2
// steps now covers ~1280cy >= cold-HBM latency. Sync identical to R13: stagek = 4
// global_load_lds; prologue vmcnt(4); per-step end vmcnt(4) (S(kt2+1) retired,
// S(kt2+2) in flight), vmcnt(0) at kt2==2; raw s_barrier + empty-asm memory fence
// after each barrier (the R12 race fix: stops the compiler hoisting the next stage
// above the barrier into a slot other waves still read).
__global__ __launch_bounds__(512, 1) void gram256_kernel(
    const unsigned char* __restrict__ packed,
    float* __restrict__ row_s,
    float* __restrict__ pos_out)
{
    __shared__ unsigned char sbuf[3][32][1024];   // 96 KB ring: 0..15 = A, 16..31 = B
    __shared__ float rsum_lds[8][64];             // per-wave row partials
    __shared__ float csum_lds[8][128];            // per-wave col partials

    const int tid  = threadIdx.x;
    const int w    = tid >> 6;           // 0..7
    const int lane = tid & 63;
    const int q    = lane >> 4;
    const int l15  = lane & 15;
    const int wr   = w >> 1;             // 0..3: 64-row band
    const int wc   = w & 1;              // 0..1: 128-col band

    // ---- XCD-bijective swizzle: 528 = 8 XCDs x 66 tiles, contiguous run per XCD ----
    const int b = ((int)blockIdx.x & 7) * 66 + ((int)blockIdx.x >> 3);

    // ---- upper-triangle decode over 32x32 tile grid: b -> (ti, tj), ti<=tj ----
    int ti = (int)(32.5f - sqrtf(32.5f * 32.5f - 2.0f * (float)b));
    while ((ti + 1) * 32 - ((ti + 1) * ti) / 2 <= b) ++ti;
    while (ti * 32 - (ti * (ti - 1)) / 2 > b) --ti;
    const int tj = ti + (b - (ti * 32 - (ti * (ti - 1)) / 2));
    const int r0 = ti * 256, c0 = tj * 256;
    const bool diag  = (ti == tj);
    const bool ptile = (tj == ti + 16);   // contains positive-pair diagonal (offset 4096)

    // staging sources: wave w stages fragments f = 4w..4w+3 (32 total), 16B/lane
    const unsigned char* sbase[4];
    #pragma unroll
    for (int si = 0; si < 4; ++si) {
        const int f = w * 4 + si;
        const int g = (f < 16) ? (ti * 16 + f) : (tj * 16 + (f - 16));
        sbase[si] = packed + (size_t)g * 4096 + (size_t)lane * 16;   // kt2=0 super-frag
    }
    auto stagek = [&](int slot, int kt2) {
        #pragma unroll
        for (int si = 0; si < 4; ++si) {
            const int f = w * 4 + si;
            __builtin_amdgcn_global_load_lds(
                (const u32_glb*)(sbase[si] + kt2 * 1024),
                (u32_lds*)&sbuf[slot][f][0], 16, 0, 0);
        }
    };

    f32x4 acc[4][8];
    #pragma unroll
    for (int mi = 0; mi < 4; ++mi)
        #pragma unroll
        for (int ni = 0; ni < 8; ++ni)
            acc[mi][ni] = (f32x4){0.f, 0.f, 0.f, 0.f};

    // prologue: fill ring slots 0,1 (kt2=0,1); wait for kt2=0's group only
    stagek(0, 0);
    stagek(1, 1);
    asm volatile("s_waitcnt vmcnt(4)" ::: "memory");
    __builtin_amdgcn_s_barrier();
    asm volatile("" ::: "memory");   // fence: no memory op hoists above the barrier

    for (int kt2 = 0; kt2 < 4; ++kt2) {
        if (kt2 < 2) stagek((kt2 + 2) % 3, kt2 + 2);   // 2-ahead prefetch

        #pragma unroll
        for (int s = 0; s < 2; ++s) {                  // two K=32 sub-steps
            long af[4], bfr[8];
            #pragma unroll
            for (int mi = 0; mi < 4; ++mi)
                af[mi] = *(const long*)&sbuf[kt2 % 3][wr * 4 + mi][s * 512 + lane * 8];
            #pragma unroll
            for (int ni = 0; ni < 8; ++ni)
                bfr[ni] = *(const long*)&sbuf[kt2 % 3][16 + wc * 8 + ni][s * 512 + lane * 8];

            #pragma unroll
            for (int mi = 0; mi < 4; ++mi)
                #pragma unroll
                for (int ni = 0; ni < 8; ++ni)
                    acc[mi][ni] = __builtin_amdgcn_mfma_f32_16x16x32_fp8_fp8(
                        af[mi], bfr[ni], acc[mi][ni], 0, 0, 0);
        }

        // counted wait: S(kt2+1) (oldest outstanding) retired; S(kt2+2) in flight
        if (kt2 < 2)       asm volatile("s_waitcnt vmcnt(4)" ::: "memory");
        else if (kt2 == 2) asm volatile("s_waitcnt vmcnt(0)" ::: "memory");
        if (kt2 < 3) {
            __builtin_amdgcn_s_barrier();
            asm volatile("" ::: "memory");   // fence: next stage stays below barrier
        }
    }

    // ---- epilogue: exp, diag mask, positive extraction, row+col partial sums ----
    // C/D layout (16x16): col = lane&15, row = q*4 + r
    float rsum[4][4];
    float csum[8] = {0.f, 0.f, 0.f, 0.f, 0.f, 0.f, 0.f, 0.f};
    #pragma unroll
    for (int mi = 0; mi < 4; ++mi)
        #pragma unroll
        for (int r = 0; r < 4; ++r) rsum[mi][r] = 0.0f;

    #pragma unroll
    for (int mi = 0; mi < 4; ++mi)
        #pragma unroll
        for (int ni = 0; ni < 8; ++ni)
            #pragma unroll
            for (int r = 0; r < 4; ++r) {
                const int lr = wr * 64 + mi * 16 + q * 4 + r;    // local row in 256
                const int lc = wc * 128 + ni * 16 + l15;         // local col in 256
                float e = __builtin_amdgcn_exp2f(acc[mi][ni][r] * TEN_LOG2E);
                if (diag && lr == lc) e = 0.0f;                  // mask self-similarity
                rsum[mi][r] += e;
                csum[ni]    += e;
                if (ptile && lr == lc) {                         // positive: col=row+4096
                    const float v = acc[mi][ni][r] * 10.0f;
                    pos_out[r0 + lr] = v;
                    pos_out[c0 + lr] = v;
                }
            }

    // row partials: reduce across 16 lanes (cols) per quad; lanes l15==0 store 64 rows
    #pragma unroll
    for (int mi = 0; mi < 4; ++mi)
        #pragma unroll
        for (int r = 0; r < 4; ++r) {
            float v = rsum[mi][r];
            v += __shfl_xor(v, 1, 64);
            v += __shfl_xor(v, 2, 64);
            v += __shfl_xor(v, 4, 64);
            v += __shfl_xor(v, 8, 64);
            if (l15 == 0) rsum_lds[w][mi * 16 + q * 4 + r] = v;
        }
    // col partials: reduce across 4 row-quads; lanes 0..15 store 128 cols
    #pragma unroll
    for (int ni = 0; ni < 8; ++ni) {
        float v = csum[ni];
        v += __shfl_xor(v, 16, 64);
        v += __shfl_xor(v, 32, 64);
        if (lane < 16) csum_lds[w][ni * 16 + l15] = v;
    }

    __syncthreads();

    // combine wave partials; one global atomic per row (tid<256) / per col (tid>=256)
    if (tid < 256) {
        const int rr  = tid & 63;
        const int wr2 = tid >> 6;
        const float v = rsum_lds[wr2 * 2 + 0][rr] + rsum_lds[wr2 * 2 + 1][rr];
        atomicAdd(&row_s[r0 + tid], v);
    } else if (!diag) {
        const int c   = tid - 256;
        const int wcc = c >> 7;
        const int cc  = c & 127;
        const float v = csum_lds[0 * 2 + wcc][cc] + csum_lds[1 * 2 + wcc][cc]
                      + csum_lds[2 * 2 + wcc][cc] + csum_lds[3 * 2 + wcc][cc];
        atomicAdd(&row_s[c0 + c], v);
    }
}

// ---------------- Kernel 3: finalize loss ----------------
__global__ __launch_bounds__(256) void finalize_kernel(
    const float* __restrict__ row_s, const float* __restrict__ pos,
    float* __restrict__ out)
{
    const int i = blockIdx.x * 256 + threadIdx.x;   // float4 index, 2048 total
    float4 s = ((const float4*)row_s)[i];
    float4 p = ((const float4*)pos)[i];
    float local = (__logf(s.x) - p.x) + (__logf(s.y) - p.y)
                + (__logf(s.z) - p.z) + (__logf(s.w) - p.w);
    #pragma unroll
    for (int off = 32; off > 0; off >>= 1) local += __shfl_xor(local, off, 64);
    __shared__ float red[4];
    if ((threadIdx.x & 63) == 0) red[threadIdx.x >> 6] = local;
    __syncthreads();
    if (threadIdx.x == 0)
        atomicAdd(out, (red[0] + red[1] + red[2] + red[3]) * (1.0f / 8192.0f));
}

// ---------------- Launch ----------------
extern "C" void kernel_launch(void* const* d_in, const int* in_sizes, int n_in,
                              void* d_out, int out_size, void* d_ws, size_t ws_size,
                              hipStream_t stream)
{
    const float* zi = (const float*)d_in[0];
    const float* zj = (const float*)d_in[1];

    unsigned char* packed = (unsigned char*)d_ws;                      // 2 MB fp8 fragment-order
    float* row_s   = (float*)((char*)d_ws + (4u << 20));               // 8192 fp32
    float* pos     = (float*)((char*)d_ws + (4u << 20) + (32u << 10)); // 8192 fp32
    float* out     = (float*)d_out;

    hipLaunchKernelGGL(normalize_pack_kernel, dim3(512), dim3(256), 0, stream,
                       zi, zj, packed, row_s, out);
    hipLaunchKernelGGL(gram256_kernel, dim3(528), dim3(512), 0, stream,
                       packed, row_s, pos);
    hipLaunchKernelGGL(finalize_kernel, dim3(8), dim3(256), 0, stream, row_s, pos, out);
}

// Round 15
// 94.614 us; speedup vs baseline: 1.1532x; 1.0097x over previous
//
#include <hip/hip_runtime.h>
#include <hip/hip_bf16.h>
#include <stdint.h>

typedef float f32x4 __attribute__((ext_vector_type(4)));
typedef unsigned long u64x2 __attribute__((ext_vector_type(2)));

static constexpr int DDIM = 256;
static constexpr float TEN_LOG2E = 14.4269504088896340736f; // 10 * log2(e)

using u32_glb = __attribute__((address_space(1))) unsigned int;
using u32_lds = __attribute__((address_space(3))) unsigned int;

// ---------------- Kernel 1: normalize + pack fp8 into MFMA-fragment order -----------
// 512 blocks x 256 threads; block g handles rows [16g, 16g+16). fp8 e4m3, half the
// panel bytes at identical MFMA rate. Super-fragment layout: group g, kt2 in 0..3 ->
// 1KB block at packed + g*4096 + kt2*1024; bytes [0,512) = frag kt=2*kt2, [512,1024)
// = frag kt=2*kt2+1 (fragment-lane f at f*8: P8[16g+(f&15)][kt*32+(f>>4)*8+j]).
// Also zero-inits row_s[8192] (blocks 0..7) and out[0] (block 0).
__global__ __launch_bounds__(256) void normalize_pack_kernel(
    const float* __restrict__ zi, const float* __restrict__ zj,
    unsigned char* __restrict__ packed, float* __restrict__ row_s, float* __restrict__ out)
{
    __shared__ unsigned char lds8[16 * 256];   // fp8 row-major for this group

    if (blockIdx.x < 8) {
        ((float4*)row_s)[blockIdx.x * 256 + threadIdx.x] = (float4){0.f, 0.f, 0.f, 0.f};
        if (blockIdx.x == 0 && threadIdx.x == 0) out[0] = 0.0f;
    }

    const int t = threadIdx.x;
    const int r = t >> 4;            // 0..15: row within group
    const int c = t & 15;            // 16 threads per row
    const int row = blockIdx.x * 16 + r;
    const float* src = (row < 4096) ? (zi + (size_t)row * DDIM)
                                    : (zj + (size_t)(row - 4096) * DDIM);
    float4 v[4];
    #pragma unroll
    for (int j = 0; j < 4; ++j) v[j] = ((const float4*)src)[c + j * 16];

    float ss = 0.0f;
    #pragma unroll
    for (int j = 0; j < 4; ++j)
        ss += v[j].x * v[j].x + v[j].y * v[j].y + v[j].z * v[j].z + v[j].w * v[j].w;
    ss += __shfl_xor(ss, 1, 64);
    ss += __shfl_xor(ss, 2, 64);
    ss += __shfl_xor(ss, 4, 64);
    ss += __shfl_xor(ss, 8, 64);
    const float inv = 1.0f / fmaxf(sqrtf(ss), 1e-8f);

    // convert 4 floats -> 4 fp8 bytes (v_cvt_pk_fp8_f32: word0 = {x,y}, word1 = {z,w})
    #pragma unroll
    for (int j = 0; j < 4; ++j) {
        int pk = __builtin_amdgcn_cvt_pk_fp8_f32(v[j].x * inv, v[j].y * inv, 0, 0);
        pk     = __builtin_amdgcn_cvt_pk_fp8_f32(v[j].z * inv, v[j].w * inv, pk, 1);
        *(unsigned int*)(lds8 + r * 256 + c * 4 + j * 64) = (unsigned int)pk;
    }
    __syncthreads();

    // repack: 4 super-frags x 64 slots of 16B; thread t -> (kt2 = t>>6, slot p = t&63)
    {
        const int kt2 = t >> 6;
        const int p   = t & 63;
        const int kt  = kt2 * 2 + (p >> 5);
        const int pp  = p & 31;
        const int fl0 = pp * 2, fl1 = pp * 2 + 1;
        u64x2 o;
        o.x = *(const unsigned long*)(lds8 + (fl0 & 15) * 256 + kt * 32 + (fl0 >> 4) * 8);
        o.y = *(const unsigned long*)(lds8 + (fl1 & 15) * 256 + kt * 32 + (fl1 >> 4) * 8);
        *(u64x2*)(packed + (size_t)(blockIdx.x * 4 + kt2) * 1024 + (size_t)p * 16) = o;
    }
}

// ---------------- Kernel 2: 256x256 fp8 tiles, 16 waves, 4 waves/SIMD ---------------
// TLP experiment: every previous gram variant ran acc[4][8]=128 AGPR -> ~250 regs/wave
// -> 2 waves/SIMD -> Occupancy ~14%, and all four other axes (schedule, XCD locality,
// in-flight depth, byte volume) tied at 36-53us -> exposed latency with nothing to
// hide behind. Here: 16 waves x 1024 threads, wave grid 4x4, per-wave 64x64 output ->
// acc[4][4] = 64 AGPR, ~110 regs total; __launch_bounds__(1024,4) targets <=128 regs
// -> 4 waves/SIMD, 16 waves/CU = 2x TLP. Tile decomposition, fp8 super-frag ring-3,
// counted vmcnt + raw barrier + hoist fence: all verified R13/R14 pieces. Staging is
// now 2 global_load_lds per wave (32 frags / 16 waves) -> re-derived counts:
// prologue vmcnt(2); end-of-kt2<2 vmcnt(2) (S(kt2+1) retired, S(kt2+2)'s 2 in
// flight); kt2==2 vmcnt(0). LDS 104KB -> 1 block/CU (16 waves from this block).
__global__ __launch_bounds__(1024, 4) void gram256_kernel(
    const unsigned char* __restrict__ packed,
    float* __restrict__ row_s,
    float* __restrict__ pos_out)
{
    __shared__ unsigned char sbuf[3][32][1024];   // 96 KB ring: 0..15 = A, 16..31 = B
    __shared__ float rsum_lds[16][64];            // per-wave row partials
    __shared__ float csum_lds[16][64];            // per-wave col partials

    const int tid  = threadIdx.x;
    const int w    = tid >> 6;           // 0..15
    const int lane = tid & 63;
    const int q    = lane >> 4;
    const int l15  = lane & 15;
    const int wr   = w >> 2;             // 0..3: 64-row band
    const int wc   = w & 3;              // 0..3: 64-col band

    // ---- XCD-bijective swizzle: 528 = 8 XCDs x 66 tiles, contiguous run per XCD ----
    const int b = ((int)blockIdx.x & 7) * 66 + ((int)blockIdx.x >> 3);

    // ---- upper-triangle decode over 32x32 tile grid: b -> (ti, tj), ti<=tj ----
    int ti = (int)(32.5f - sqrtf(32.5f * 32.5f - 2.0f * (float)b));
    while ((ti + 1) * 32 - ((ti + 1) * ti) / 2 <= b) ++ti;
    while (ti * 32 - (ti * (ti - 1)) / 2 > b) --ti;
    const int tj = ti + (b - (ti * 32 - (ti * (ti - 1)) / 2));
    const int r0 = ti * 256, c0 = tj * 256;
    const bool diag  = (ti == tj);
    const bool ptile = (tj == ti + 16);   // contains positive-pair diagonal (offset 4096)

    // staging sources: wave w stages fragments f = 2w, 2w+1 (32 total), 16B/lane
    const unsigned char* sbase[2];
    #pragma unroll
    for (int si = 0; si < 2; ++si) {
        const int f = w * 2 + si;
        const int g = (f < 16) ? (ti * 16 + f) : (tj * 16 + (f - 16));
        sbase[si] = packed + (size_t)g * 4096 + (size_t)lane * 16;   // kt2=0 super-frag
    }
    auto stagek = [&](int slot, int kt2) {
        #pragma unroll
        for (int si = 0; si < 2; ++si) {
            const int f = w * 2 + si;
            __builtin_amdgcn_global_load_lds(
                (const u32_glb*)(sbase[si] + kt2 * 1024),
                (u32_lds*)&sbuf[slot][f][0], 16, 0, 0);
        }
    };

    f32x4 acc[4][4];
    #pragma unroll
    for (int mi = 0; mi < 4; ++mi)
        #pragma unroll
        for (int ni = 0; ni < 4; ++ni)
            acc[mi][ni] = (f32x4){0.f, 0.f, 0.f, 0.f};

    // prologue: fill ring slots 0,1 (kt2=0,1); wait for kt2=0's group (2 ops) only
    stagek(0, 0);
    stagek(1, 1);
    asm volatile("s_waitcnt vmcnt(2)" ::: "memory");
    __builtin_amdgcn_s_barrier();
    asm volatile("" ::: "memory");   // fence: no memory op hoists above the barrier

    for (int kt2 = 0; kt2 < 4; ++kt2) {
        if (kt2 < 2) stagek((kt2 + 2) % 3, kt2 + 2);   // 2-ahead prefetch

        #pragma unroll
        for (int s = 0; s < 2; ++s) {                  // two K=32 sub-steps
            long af[4], bfr[4];
            #pragma unroll
            for (int mi = 0; mi < 4; ++mi)
                af[mi] = *(const long*)&sbuf[kt2 % 3][wr * 4 + mi][s * 512 + lane * 8];
            #pragma unroll
            for (int ni = 0; ni < 4; ++ni)
                bfr[ni] = *(const long*)&sbuf[kt2 % 3][16 + wc * 4 + ni][s * 512 + lane * 8];

            #pragma unroll
            for (int mi = 0; mi < 4; ++mi)
                #pragma unroll
                for (int ni = 0; ni < 4; ++ni)
                    acc[mi][ni] = __builtin_amdgcn_mfma_f32_16x16x32_fp8_fp8(
                        af[mi], bfr[ni], acc[mi][ni], 0, 0, 0);
        }

        // counted wait: S(kt2+1) (oldest outstanding) retired; S(kt2+2) in flight
        if (kt2 < 2)       asm volatile("s_waitcnt vmcnt(2)" ::: "memory");
        else if (kt2 == 2) asm volatile("s_waitcnt vmcnt(0)" ::: "memory");
        if (kt2 < 3) {
            __builtin_amdgcn_s_barrier();
            asm volatile("" ::: "memory");   // fence: next stage stays below barrier
        }
    }

    // ---- epilogue: exp, diag mask, positive extraction, row+col partial sums ----
    // C/D layout (16x16): col = lane&15, row = q*4 + r
    float rsum[4][4];
    float csum[4] = {0.f, 0.f, 0.f, 0.f};
    #pragma unroll
    for (int mi = 0; mi < 4; ++mi)
        #pragma unroll
        for (int r = 0; r < 4; ++r) rsum[mi][r] = 0.0f;

    #pragma unroll
    for (int mi = 0; mi < 4; ++mi)
        #pragma unroll
        for (int ni = 0; ni < 4; ++ni)
            #pragma unroll
            for (int r = 0; r < 4; ++r) {
                const int lr = wr * 64 + mi * 16 + q * 4 + r;    // local row in 256
                const int lc = wc * 64 + ni * 16 + l15;          // local col in 256
                float e = __builtin_amdgcn_exp2f(acc[mi][ni][r] * TEN_LOG2E);
                if (diag && lr == lc) e = 0.0f;                  // mask self-similarity
                rsum[mi][r] += e;
                csum[ni]    += e;
                if (ptile && lr == lc) {                         // positive: col=row+4096
                    const float v = acc[mi][ni][r] * 10.0f;
                    pos_out[r0 + lr] = v;
                    pos_out[c0 + lr] = v;
                }
            }

    // row partials: reduce across 16 lanes (cols) per quad; lanes l15==0 store 64 rows
    #pragma unroll
    for (int mi = 0; mi < 4; ++mi)
        #pragma unroll
        for (int r = 0; r < 4; ++r) {
            float v = rsum[mi][r];
            v += __shfl_xor(v, 1, 64);
            v += __shfl_xor(v, 2, 64);
            v += __shfl_xor(v, 4, 64);
            v += __shfl_xor(v, 8, 64);
            if (l15 == 0) rsum_lds[w][mi * 16 + q * 4 + r] = v;
        }
    // col partials: reduce across 4 row-quads; lanes 0..15 store 64 cols
    #pragma unroll
    for (int ni = 0; ni < 4; ++ni) {
        float v = csum[ni];
        v += __shfl_xor(v, 16, 64);
        v += __shfl_xor(v, 32, 64);
        if (lane < 16) csum_lds[w][ni * 16 + l15] = v;
    }

    __syncthreads();

    // combine wave partials: row band = tid>>6 sums its 4 col-band waves; col band
    // sums its 4 row-band waves (wave index = wr*4 + wc). One atomic per row/col.
    if (tid < 256) {
        const int band = tid >> 6;
        const int rr   = tid & 63;
        const float v = rsum_lds[band * 4 + 0][rr] + rsum_lds[band * 4 + 1][rr]
                      + rsum_lds[band * 4 + 2][rr] + rsum_lds[band * 4 + 3][rr];
        atomicAdd(&row_s[r0 + tid], v);
    } else if (tid < 512 && !diag) {
        const int c    = tid - 256;
        const int band = c >> 6;
        const int cc   = c & 63;
        const float v = csum_lds[0 * 4 + band][cc] + csum_lds[1 * 4 + band][cc]
                      + csum_lds[2 * 4 + band][cc] + csum_lds[3 * 4 + band][cc];
        atomicAdd(&row_s[c0 + c], v);
    }
}

// ---------------- Kernel 3: finalize loss ----------------
__global__ __launch_bounds__(256) void finalize_kernel(
    const float* __restrict__ row_s, const float* __restrict__ pos,
    float* __restrict__ out)
{
    const int i = blockIdx.x * 256 + threadIdx.x;   // float4 index, 2048 total
    float4 s = ((const float4*)row_s)[i];
    float4 p = ((const float4*)pos)[i];
    float local = (__logf(s.x) - p.x) + (__logf(s.y) - p.y)
                + (__logf(s.z) - p.z) + (__logf(s.w) - p.w);
    #pragma unroll
    for (int off = 32; off > 0; off >>= 1) local += __shfl_xor(local, off, 64);
    __shared__ float red[4];
    if ((threadIdx.x & 63) == 0) red[threadIdx.x >> 6] = local;
    __syncthreads();
    if (threadIdx.x == 0)
        atomicAdd(out, (red[0] + red[1] + red[2] + red[3]) * (1.0f / 8192.0f));
}

// ---------------- Launch ----------------
extern "C" void kernel_launch(void* const* d_in, const int* in_sizes, int n_in,
                              void* d_out, int out_size, void* d_ws, size_t ws_size,
                              hipStream_t stream)
{
    const float* zi = (const float*)d_in[0];
    const float* zj = (const float*)d_in[1];

    unsigned char* packed = (unsigned char*)d_ws;                      // 2 MB fp8 fragment-order
    float* row_s   = (float*)((char*)d_ws + (4u << 20));               // 8192 fp32
    float* pos     = (float*)((char*)d_ws + (4u << 20) + (32u << 10)); // 8192 fp32
    float* out     = (float*)d_out;

    hipLaunchKernelGGL(normalize_pack_kernel, dim3(512), dim3(256), 0, stream,
                       zi, zj, packed, row_s, out);
    hipLaunchKernelGGL(gram256_kernel, dim3(528), dim3(1024), 0, stream,
                       packed, row_s, pos);
    hipLaunchKernelGGL(finalize_kernel, dim3(8), dim3(256), 0, stream, row_s, pos, out);
}